// Round 2
// baseline (202.229 us; speedup 1.0000x reference)
//
#include <hip/hip_runtime.h>

// Problem constants (fixed by the reference file)
#define NN 8192
#define DIN 256
#define DD 256
static const long long PP = (long long)NN * (NN - 1) / 2;   // 33,550,336

typedef float __attribute__((ext_vector_type(4))) fx4;      // nontemporal-store-able

// ---------------------------------------------------------------------------
// Kernel 1: combine weights.
//   M[i][0..1] = sum_j W_enc[i][j] * W_cls[j][0..1]        (A projection)
//   M[i][2..3] = sum_j W_enc[i][j] * W_cls[256+j][0..1]    (B projection)
//   off[0..1]  = b_enc . W_cls[:256][:,c] + b_cls[c]
//   off[2..3]  = b_enc . W_cls[256:][:,c]
// One block of 256 threads.
// ---------------------------------------------------------------------------
__global__ __launch_bounds__(256) void combine_kernel(
    const float* __restrict__ W_enc,   // [256][256]
    const float* __restrict__ b_enc,   // [256]
    const float* __restrict__ W_cls,   // [512][2]
    const float* __restrict__ b_cls,   // [2]
    float* __restrict__ M,             // [256][4]
    float* __restrict__ off)           // [4]
{
    __shared__ float wc[1024];         // W_cls staged: [512][2]
    const int tid = threadIdx.x;
    for (int i = tid; i < 1024; i += 256) wc[i] = W_cls[i];
    __syncthreads();

    float a0 = 0.f, a1 = 0.f, a2 = 0.f, a3 = 0.f;
    const float* wrow = W_enc + (long long)tid * DIN;
    #pragma unroll 4
    for (int j = 0; j < DIN; ++j) {
        const float we = wrow[j];
        a0 += we * wc[j * 2 + 0];
        a1 += we * wc[j * 2 + 1];
        a2 += we * wc[(DD + j) * 2 + 0];
        a3 += we * wc[(DD + j) * 2 + 1];
    }
    ((float4*)M)[tid] = make_float4(a0, a1, a2, a3);

    if (tid < 4) {
        const int c = tid & 1;
        const int base = (tid < 2) ? 0 : DD;
        float o = 0.f;
        for (int j = 0; j < DIN; ++j) o += b_enc[j] * wc[(base + j) * 2 + c];
        if (tid < 2) o += b_cls[tid];     // fold b_cls into the A half
        off[tid] = o;
    }
}

// ---------------------------------------------------------------------------
// Kernel 2: per-node projections.
//   AB[n] = { A0, A1, B0, B1 } = nodes[n] @ M + off
// ---------------------------------------------------------------------------
__global__ __launch_bounds__(256) void ab_kernel(
    const float* __restrict__ nodes,   // [8192][256]
    const float* __restrict__ Mg,      // [256][4]
    const float* __restrict__ offg,    // [4]
    float4* __restrict__ AB)           // [8192]
{
    __shared__ float Ms[1024];
    __shared__ float offs[4];
    const int tid = threadIdx.x;
    for (int i = tid; i < 1024; i += 256) Ms[i] = Mg[i];
    if (tid < 4) offs[tid] = offg[tid];
    __syncthreads();

    for (int n = blockIdx.x * 256 + tid; n < NN; n += gridDim.x * 256) {
        float a0 = offs[0], a1 = offs[1], a2 = offs[2], a3 = offs[3];
        const float4* row = (const float4*)(nodes + (long long)n * DIN);
        #pragma unroll 8
        for (int i = 0; i < DIN / 4; ++i) {
            const float4 v = row[i];
            const int j = i * 4;
            a0 += v.x * Ms[(j + 0) * 4 + 0] + v.y * Ms[(j + 1) * 4 + 0]
                + v.z * Ms[(j + 2) * 4 + 0] + v.w * Ms[(j + 3) * 4 + 0];
            a1 += v.x * Ms[(j + 0) * 4 + 1] + v.y * Ms[(j + 1) * 4 + 1]
                + v.z * Ms[(j + 2) * 4 + 1] + v.w * Ms[(j + 3) * 4 + 1];
            a2 += v.x * Ms[(j + 0) * 4 + 2] + v.y * Ms[(j + 1) * 4 + 2]
                + v.z * Ms[(j + 2) * 4 + 2] + v.w * Ms[(j + 3) * 4 + 2];
            a3 += v.x * Ms[(j + 0) * 4 + 3] + v.y * Ms[(j + 1) * 4 + 3]
                + v.z * Ms[(j + 2) * 4 + 3] + v.w * Ms[(j + 3) * 4 + 3];
        }
        AB[n] = make_float4(a0, a1, a2, a3);
    }
}

// ---------------------------------------------------------------------------
// Kernel 3: fill all P pairs.  Thread handles 4 consecutive pair indices.
//   y[2p+c]  = A[s][c] + B[t][c]
//   yt[p]    = 0
// p0 is a multiple of 4 -> y+2*p0 is 32B aligned, yt+p0 is 16B aligned.
// ---------------------------------------------------------------------------
__global__ __launch_bounds__(256) void fill_kernel(
    const float4* __restrict__ AB,     // [8192] {A0,A1,B0,B1}
    float* __restrict__ y,             // [P][2]
    float* __restrict__ yt)            // [P]
{
    const long long p0 = ((long long)blockIdx.x * 256 + threadIdx.x) * 4;

    // invert p0 -> (s, t):  s = floor((M - sqrt(M^2 - 8 p0)) / 2), M = 2N-1
    const double Md = (double)(2 * NN - 1);
    int s = (int)((Md - sqrt(Md * Md - 8.0 * (double)p0)) * 0.5);
    long long rs = (long long)s * (2 * NN - s - 1) / 2;
    // safety fixups (should not iterate; exactness argued analytically)
    while (p0 < rs)                { --s; rs = (long long)s * (2 * NN - s - 1) / 2; }
    while (p0 >= rs + (NN - 1 - s)) { rs += NN - 1 - s; ++s; }
    int t = (int)(p0 - rs) + s + 1;

    float4 ab = AB[s];
    float ax = ab.x, ay = ab.y;

    float o[8];
    #pragma unroll
    for (int k = 0; k < 4; ++k) {
        const float4 bb = AB[t];
        o[2 * k + 0] = ax + bb.z;
        o[2 * k + 1] = ay + bb.w;
        if (++t == NN) {               // row crossing (rare)
            ++s;
            t = s + 1;
            const float4 ab2 = AB[s];
            ax = ab2.x; ay = ab2.y;
        }
    }

    fx4* yp = (fx4*)(y + 2 * p0);
    fx4 v0 = {o[0], o[1], o[2], o[3]};
    fx4 v1 = {o[4], o[5], o[6], o[7]};
    fx4 vz = {0.f, 0.f, 0.f, 0.f};
    __builtin_nontemporal_store(v0, yp + 0);
    __builtin_nontemporal_store(v1, yp + 1);
    __builtin_nontemporal_store(vz, (fx4*)(yt + p0));
}

// ---------------------------------------------------------------------------
// Kernel 4: scatter edge labels.  yt[pair_idx] = 1.0 for valid (u < v) edges.
// ---------------------------------------------------------------------------
__global__ __launch_bounds__(256) void edge_kernel(
    const int* __restrict__ edges,     // [2][E]
    float* __restrict__ yt,
    int E)
{
    const int e = blockIdx.x * 256 + threadIdx.x;
    if (e >= E) return;
    const int u = edges[e];
    const int v = edges[E + e];
    if (u < v) {
        const long long idx = (long long)u * (2 * NN - u - 1) / 2 + (v - u - 1);
        yt[idx] = 1.0f;
    }
}

extern "C" void kernel_launch(void* const* d_in, const int* in_sizes, int n_in,
                              void* d_out, int out_size, void* d_ws, size_t ws_size,
                              hipStream_t stream) {
    const float* nodes = (const float*)d_in[0];
    const int*   edges = (const int*)d_in[1];
    const float* W_enc = (const float*)d_in[2];
    const float* b_enc = (const float*)d_in[3];
    const float* W_cls = (const float*)d_in[4];
    const float* b_cls = (const float*)d_in[5];
    const int E = in_sizes[1] / 2;

    float* ws   = (float*)d_ws;
    float* M    = ws;               // 1024 floats
    float* off  = ws + 1024;        // 4 floats
    float4* AB  = (float4*)(ws + 2048);  // 8192 float4 (16B aligned)

    float* y  = (float*)d_out;                    // [P][2]
    float* yt = (float*)d_out + 2 * PP;           // [P]

    combine_kernel<<<1, 256, 0, stream>>>(W_enc, b_enc, W_cls, b_cls, M, off);
    ab_kernel<<<32, 256, 0, stream>>>(nodes, M, off, AB);

    const int fill_blocks = (int)(PP / 1024);     // P = 1024 * 32764 exactly
    fill_kernel<<<fill_blocks, 256, 0, stream>>>(AB, y, yt);

    edge_kernel<<<(E + 255) / 256, 256, 0, stream>>>(edges, yt, E);
}

// Round 3
// 95.003 us; speedup vs baseline: 2.1287x; 2.1287x over previous
//
#include <hip/hip_runtime.h>

// Problem constants (fixed by the reference file)
#define NN 8192
#define DIN 256
#define DD 256
static const long long PP = (long long)NN * (NN - 1) / 2;   // 33,550,336

typedef float __attribute__((ext_vector_type(4))) fx4;      // nontemporal-store-able
typedef float __attribute__((ext_vector_type(2))) fx2;

// ---------------------------------------------------------------------------
// Kernel 1: per-node projections, with the weight-combine fused in.
// Each block redundantly computes in LDS:
//   M[i][0..1] = sum_j W_enc[i][j] * W_cls[j][0..1]        (A projection)
//   M[i][2..3] = sum_j W_enc[i][j] * W_cls[256+j][0..1]    (B projection)
//   off[0..1]  = b_enc . W_cls[:256][:,c] + b_cls[c]
//   off[2..3]  = b_enc . W_cls[256:][:,c]
// then AB[n] = { A0, A1, B0, B1 } = nodes[n] @ M + off  for its node slice.
// ---------------------------------------------------------------------------
__global__ __launch_bounds__(256) void ab_kernel(
    const float* __restrict__ nodes,   // [8192][256]
    const float* __restrict__ W_enc,   // [256][256]
    const float* __restrict__ b_enc,   // [256]
    const float* __restrict__ W_cls,   // [512][2]
    const float* __restrict__ b_cls,   // [2]
    float4* __restrict__ AB)           // [8192] out
{
    __shared__ float wc[1024];         // W_cls staged: [512][2]
    __shared__ float Ms[1024];         // M [256][4]
    __shared__ float offs[4];
    const int tid = threadIdx.x;
    for (int i = tid; i < 1024; i += 256) wc[i] = W_cls[i];
    __syncthreads();

    // --- M row `tid` ---
    {
        float a0 = 0.f, a1 = 0.f, a2 = 0.f, a3 = 0.f;
        const float4* wrow = (const float4*)(W_enc + (long long)tid * DIN);
        #pragma unroll 8
        for (int i = 0; i < DIN / 4; ++i) {
            const float4 v = wrow[i];
            const int j = i * 4;
            a0 += v.x * wc[(j+0)*2+0] + v.y * wc[(j+1)*2+0]
                + v.z * wc[(j+2)*2+0] + v.w * wc[(j+3)*2+0];
            a1 += v.x * wc[(j+0)*2+1] + v.y * wc[(j+1)*2+1]
                + v.z * wc[(j+2)*2+1] + v.w * wc[(j+3)*2+1];
            a2 += v.x * wc[(DD+j+0)*2+0] + v.y * wc[(DD+j+1)*2+0]
                + v.z * wc[(DD+j+2)*2+0] + v.w * wc[(DD+j+3)*2+0];
            a3 += v.x * wc[(DD+j+0)*2+1] + v.y * wc[(DD+j+1)*2+1]
                + v.z * wc[(DD+j+2)*2+1] + v.w * wc[(DD+j+3)*2+1];
        }
        Ms[tid*4+0] = a0; Ms[tid*4+1] = a1; Ms[tid*4+2] = a2; Ms[tid*4+3] = a3;
    }

    // --- off (threads 0..3) ---
    if (tid < 4) {
        const int c = tid & 1;
        const int base = (tid < 2) ? 0 : DD;
        float o0 = 0.f, o1 = 0.f, o2 = 0.f, o3 = 0.f;
        for (int j = 0; j < DIN; j += 4) {
            o0 += b_enc[j+0] * wc[(base+j+0)*2+c];
            o1 += b_enc[j+1] * wc[(base+j+1)*2+c];
            o2 += b_enc[j+2] * wc[(base+j+2)*2+c];
            o3 += b_enc[j+3] * wc[(base+j+3)*2+c];
        }
        float o = (o0 + o1) + (o2 + o3);
        if (tid < 2) o += b_cls[tid];     // fold b_cls into the A half
        offs[tid] = o;
    }
    __syncthreads();

    // --- per-node projections ---
    for (int n = blockIdx.x * 256 + tid; n < NN; n += gridDim.x * 256) {
        float a0 = offs[0], a1 = offs[1], a2 = offs[2], a3 = offs[3];
        const float4* row = (const float4*)(nodes + (long long)n * DIN);
        #pragma unroll 8
        for (int i = 0; i < DIN / 4; ++i) {
            const float4 v = row[i];
            const int j = i * 4;
            a0 += v.x * Ms[(j + 0) * 4 + 0] + v.y * Ms[(j + 1) * 4 + 0]
                + v.z * Ms[(j + 2) * 4 + 0] + v.w * Ms[(j + 3) * 4 + 0];
            a1 += v.x * Ms[(j + 0) * 4 + 1] + v.y * Ms[(j + 1) * 4 + 1]
                + v.z * Ms[(j + 2) * 4 + 1] + v.w * Ms[(j + 3) * 4 + 1];
            a2 += v.x * Ms[(j + 0) * 4 + 2] + v.y * Ms[(j + 1) * 4 + 2]
                + v.z * Ms[(j + 2) * 4 + 2] + v.w * Ms[(j + 3) * 4 + 2];
            a3 += v.x * Ms[(j + 0) * 4 + 3] + v.y * Ms[(j + 1) * 4 + 3]
                + v.z * Ms[(j + 2) * 4 + 3] + v.w * Ms[(j + 3) * 4 + 3];
        }
        AB[n] = make_float4(a0, a1, a2, a3);
    }
}

// ---------------------------------------------------------------------------
// Kernel 2: fill all P pairs.  Thread g handles pairs {2g, 2g+1}:
//   one fully lane-contiguous fx4 store to y + 4g   (full 64-B lines/instr)
//   one fully lane-contiguous fx2 zero  to yt + 2g
// ---------------------------------------------------------------------------
__global__ __launch_bounds__(256) void fill_kernel(
    const float4* __restrict__ AB,     // [8192] {A0,A1,B0,B1}
    float* __restrict__ y,             // [P][2]
    float* __restrict__ yt)            // [P]
{
    const long long g  = (long long)blockIdx.x * 256 + threadIdx.x;
    const long long p0 = 2 * g;

    // invert p0 -> (s, t):  s = floor((M - sqrt(M^2 - 8 p0)) / 2), M = 2N-1
    const double Md = (double)(2 * NN - 1);
    int s = (int)((Md - sqrt(Md * Md - 8.0 * (double)p0)) * 0.5);
    if (s < 0) s = 0;
    if (s > NN - 2) s = NN - 2;
    long long rs = (long long)s * (2 * NN - s - 1) / 2;
    // safety fixups (≤1 iteration expected; robust to sqrt rounding)
    while (p0 < rs)                 { --s; rs -= NN - 1 - s; }
    while (p0 >= rs + (NN - 1 - s)) { rs += NN - 1 - s; ++s; }
    int t = (int)(p0 - rs) + s + 1;

    float4 a  = AB[s];
    float4 b0 = AB[t];
    const float o0 = a.x + b0.z, o1 = a.y + b0.w;

    if (++t == NN) {                   // row crossing (rare)
        ++s; t = s + 1;
        a = AB[s];
    }
    float4 b1 = AB[t];
    const float o2 = a.x + b1.z, o3 = a.y + b1.w;

    fx4 v = {o0, o1, o2, o3};
    __builtin_nontemporal_store(v, (fx4*)(y + 4 * g));
    fx2 z = {0.f, 0.f};
    __builtin_nontemporal_store(z, (fx2*)(yt + 2 * g));
}

// ---------------------------------------------------------------------------
// Kernel 3: scatter edge labels.  yt[pair_idx] = 1.0 for valid (u < v) edges.
// ---------------------------------------------------------------------------
__global__ __launch_bounds__(256) void edge_kernel(
    const int* __restrict__ edges,     // [2][E]
    float* __restrict__ yt,
    int E)
{
    const int e = blockIdx.x * 256 + threadIdx.x;
    if (e >= E) return;
    const int u = edges[e];
    const int v = edges[E + e];
    if (u < v) {
        const long long idx = (long long)u * (2 * NN - u - 1) / 2 + (v - u - 1);
        yt[idx] = 1.0f;
    }
}

extern "C" void kernel_launch(void* const* d_in, const int* in_sizes, int n_in,
                              void* d_out, int out_size, void* d_ws, size_t ws_size,
                              hipStream_t stream) {
    const float* nodes = (const float*)d_in[0];
    const int*   edges = (const int*)d_in[1];
    const float* W_enc = (const float*)d_in[2];
    const float* b_enc = (const float*)d_in[3];
    const float* W_cls = (const float*)d_in[4];
    const float* b_cls = (const float*)d_in[5];
    const int E = in_sizes[1] / 2;

    float4* AB = (float4*)d_ws;                   // 8192 float4 (16B aligned)

    float* y  = (float*)d_out;                    // [P][2]
    float* yt = (float*)d_out + 2 * PP;           // [P]

    ab_kernel<<<32, 256, 0, stream>>>(nodes, W_enc, b_enc, W_cls, b_cls, AB);

    // P/2 = 16,775,168 = 65528 * 256 exactly
    const int fill_blocks = (int)(PP / 512);
    fill_kernel<<<fill_blocks, 256, 0, stream>>>(AB, y, yt);

    edge_kernel<<<(E + 255) / 256, 256, 0, stream>>>(edges, yt, E);
}